// Round 1
// baseline (118.950 us; speedup 1.0000x reference)
//
#include <hip/hip_runtime.h>

// out[f*N + n] = sum_d w[f*D + d] * x[n*D + d]
// F=64, N=116250, D=128, all fp32. bf16 MFMA (16x16x32), A=w (rows=f), B=x (cols=n).

#define NTOT 116250
#define DDIM 128
#define FILT 64

typedef __bf16 bf16x8 __attribute__((ext_vector_type(8)));
typedef float f32x4 __attribute__((ext_vector_type(4)));

__global__ __launch_bounds__(256) void
conv_dot_kernel(const float* __restrict__ x, const float* __restrict__ w,
                float* __restrict__ out) {
    const int tid  = threadIdx.x;
    const int wid  = tid >> 6;
    const int lane = tid & 63;
    const int lq   = lane >> 4;   // 0..3
    const int lr   = lane & 15;   // 0..15

    // ---- W fragments (A operand), held in registers for the whole kernel ----
    // a[ft][kt][j] = w[ft*16 + lr][kt*32 + lq*8 + j]  (k-slot permutation is
    // consistent between A and B loads, so any HW k-layout gives the same dot)
    bf16x8 afrag[4][4];
#pragma unroll
    for (int ft = 0; ft < 4; ++ft) {
        const float* wp = w + (ft * 16 + lr) * DDIM + lq * 8;
#pragma unroll
        for (int kt = 0; kt < 4; ++kt) {
            f32x4 lo = *reinterpret_cast<const f32x4*>(wp + kt * 32);
            f32x4 hi = *reinterpret_cast<const f32x4*>(wp + kt * 32 + 4);
            bf16x8 a;
#pragma unroll
            for (int j = 0; j < 4; ++j) {
                a[j]     = (__bf16)lo[j];
                a[j + 4] = (__bf16)hi[j];
            }
            afrag[ft][kt] = a;
        }
    }

    // Each wave streams 4 n-tiles of 16 (wave covers 64 n, block covers 256 n).
    const int nbase = blockIdx.x * 256 + wid * 64;

#pragma unroll
    for (int t = 0; t < 4; ++t) {
        const int n0 = nbase + t * 16;
        int nrow = n0 + lr;
        if (nrow > NTOT - 1) nrow = NTOT - 1;   // clamp tail loads
        const float* xp = x + (size_t)nrow * DDIM + lq * 8;

        bf16x8 bfrag[4];
#pragma unroll
        for (int kt = 0; kt < 4; ++kt) {
            f32x4 lo = *reinterpret_cast<const f32x4*>(xp + kt * 32);
            f32x4 hi = *reinterpret_cast<const f32x4*>(xp + kt * 32 + 4);
            bf16x8 b;
#pragma unroll
            for (int j = 0; j < 4; ++j) {
                b[j]     = (__bf16)lo[j];
                b[j + 4] = (__bf16)hi[j];
            }
            bfrag[kt] = b;
        }

        f32x4 acc[4] = {};
#pragma unroll
        for (int kt = 0; kt < 4; ++kt) {
#pragma unroll
            for (int ft = 0; ft < 4; ++ft) {
                acc[ft] = __builtin_amdgcn_mfma_f32_16x16x32_bf16(
                    afrag[ft][kt], bfrag[kt], acc[ft], 0, 0, 0);
            }
        }

        // D layout (m89-verified): row = (lane>>4)*4 + reg, col = lane&15.
        // row -> f (within f-tile), col -> n. Stores: 16 consecutive n per
        // 16-lane group = 64B segments, coalesced along n.
        if (n0 + lr < NTOT) {
#pragma unroll
            for (int ft = 0; ft < 4; ++ft) {
#pragma unroll
                for (int j = 0; j < 4; ++j) {
                    const int f = ft * 16 + lq * 4 + j;
                    out[f * NTOT + n0 + lr] = acc[ft][j];
                }
            }
        }
    }
}

extern "C" void kernel_launch(void* const* d_in, const int* in_sizes, int n_in,
                              void* d_out, int out_size, void* d_ws, size_t ws_size,
                              hipStream_t stream) {
    const float* x = (const float*)d_in[0];   // (1,1,N,D) fp32, 14,880,000
    const float* w = (const float*)d_in[1];   // (F,1,1,D) fp32, 8,192
    float* out = (float*)d_out;               // (F,N) fp32 row-major, 7,440,000
    const int blocks = (NTOT + 255) / 256;    // 455 blocks x 256 threads
    conv_dot_kernel<<<blocks, 256, 0, stream>>>(x, w, out);
}

// Round 2
// 104.081 us; speedup vs baseline: 1.1429x; 1.1429x over previous
//
#include <hip/hip_runtime.h>

// out[f*N + n] = sum_d w[f*D + d] * x[n*D + d]
// F=64, N=116250, D=128, fp32 in/out. bf16 MFMA 16x16x32.
// w staged in LDS (bf16, 16B-chunk XOR swizzle); one 16-n tile per wave.

#define NTOT 116250
#define DDIM 128
#define FILT 64

typedef __bf16 bf16x8 __attribute__((ext_vector_type(8)));
typedef float f32x4 __attribute__((ext_vector_type(4)));

__global__ __launch_bounds__(256) void
conv_dot_kernel(const float* __restrict__ x, const float* __restrict__ w,
                float* __restrict__ out) {
    // [64][128] bf16, row stride 256 B; chunk c (16 B) stored at c ^ (row&15)
    __shared__ __bf16 lds_w[FILT * DDIM];   // 16 KiB

    const int tid  = threadIdx.x;
    const int wid  = tid >> 6;
    const int lane = tid & 63;
    const int lq   = lane >> 4;   // 0..3
    const int lr   = lane & 15;   // 0..15

    // ---- cooperative stage: w (fp32) -> LDS (bf16, swizzled) ----
    // 1024 chunks of 8 bf16; each thread converts 4 chunks.
#pragma unroll
    for (int k = 0; k < 4; ++k) {
        const int chunk = tid + k * 256;
        const int row = chunk >> 4;     // 0..63
        const int c   = chunk & 15;     // 0..15
        const float* wp = w + row * DDIM + c * 8;
        f32x4 lo = *reinterpret_cast<const f32x4*>(wp);
        f32x4 hi = *reinterpret_cast<const f32x4*>(wp + 4);
        bf16x8 v;
#pragma unroll
        for (int j = 0; j < 4; ++j) { v[j] = (__bf16)lo[j]; v[j + 4] = (__bf16)hi[j]; }
        const int csw = c ^ (row & 15);
        *reinterpret_cast<bf16x8*>(&lds_w[row * DDIM + csw * 8]) = v;
    }
    __syncthreads();

    // ---- each wave: one 16-column n-tile ----
    const int n0 = (blockIdx.x * 4 + wid) * 16;
    int nrow = n0 + lr;
    if (nrow > NTOT - 1) nrow = NTOT - 1;        // clamp tail loads
    const float* xp = x + (size_t)nrow * DDIM + lq * 8;

    // issue all 8 x-loads in one burst (independent, 16 B each)
    f32x4 xs[8];
#pragma unroll
    for (int kt = 0; kt < 4; ++kt) {
        xs[kt * 2]     = *reinterpret_cast<const f32x4*>(xp + kt * 32);
        xs[kt * 2 + 1] = *reinterpret_cast<const f32x4*>(xp + kt * 32 + 4);
    }
    bf16x8 bfrag[4];
#pragma unroll
    for (int kt = 0; kt < 4; ++kt) {
        bf16x8 b;
#pragma unroll
        for (int j = 0; j < 4; ++j) {
            b[j]     = (__bf16)xs[kt * 2][j];
            b[j + 4] = (__bf16)xs[kt * 2 + 1][j];
        }
        bfrag[kt] = b;
    }

    // A fragments read from LDS per use: row = ft*16+lr, chunk = (kt*4+lq)^lr
    f32x4 acc[4] = {};
#pragma unroll
    for (int kt = 0; kt < 4; ++kt) {
#pragma unroll
        for (int ft = 0; ft < 4; ++ft) {
            const int row = ft * 16 + lr;
            const int csw = (kt * 4 + lq) ^ lr;   // (row&15) == lr
            bf16x8 a = *reinterpret_cast<const bf16x8*>(&lds_w[row * DDIM + csw * 8]);
            acc[ft] = __builtin_amdgcn_mfma_f32_16x16x32_bf16(a, bfrag[kt], acc[ft], 0, 0, 0);
        }
    }

    // C/D layout (m89): row=(lane>>4)*4+reg -> f, col=lane&15 -> n
    if (n0 + lr < NTOT) {
#pragma unroll
        for (int ft = 0; ft < 4; ++ft)
#pragma unroll
            for (int j = 0; j < 4; ++j)
                out[(ft * 16 + lq * 4 + j) * NTOT + n0 + lr] = acc[ft][j];
    }
}

extern "C" void kernel_launch(void* const* d_in, const int* in_sizes, int n_in,
                              void* d_out, int out_size, void* d_ws, size_t ws_size,
                              hipStream_t stream) {
    const float* x = (const float*)d_in[0];   // (1,1,N,D) fp32
    const float* w = (const float*)d_in[1];   // (F,1,1,D) fp32
    float* out = (float*)d_out;               // (F,N) fp32 row-major
    const int blocks = (NTOT + 63) / 64;      // 64 n per block (4 waves x 16)
    conv_dot_kernel<<<blocks, 256, 0, stream>>>(x, w, out);
}